// Round 1
// 218.419 us; speedup vs baseline: 1.0447x; 1.0447x over previous
//
#include <hip/hip_runtime.h>
#include <cstdint>
#include <cstddef>

#define F_IN  128
#define F_HID 64
#define F_OUT 40

#define BSH   9     // bucket = dst >> 9 (512 nodes/bucket)
#define NBMAX 256   // supports N <= 131072
#define CHUNK 4096  // edges per partition block

#define BLD_T   512   // build_k threads
#define BLD_CAP 10240 // LDS-staged edges per bucket (40 KB)

typedef __attribute__((ext_vector_type(8))) short short8;   // 8 bf16 = 4 VGPR
typedef __attribute__((ext_vector_type(4))) float f32x4;    // MFMA C/D

// bf16 <-> f32 helpers (RNE on pack; values are finite)
__device__ __forceinline__ unsigned short f2bf(float f) {
  unsigned u = __float_as_uint(f);
  u += 0x7fffu + ((u >> 16) & 1u);
  return (unsigned short)(u >> 16);
}
__device__ __forceinline__ float bf2f(unsigned short b) {
  return __uint_as_float((unsigned)b << 16);
}
__device__ __forceinline__ float bflo(unsigned u) { return __uint_as_float(u << 16); }
__device__ __forceinline__ float bfhi(unsigned u) { return __uint_as_float(u & 0xffff0000u); }
__device__ __forceinline__ unsigned packbf(float lo, float hi) {
  return (unsigned)f2bf(lo) | ((unsigned)f2bf(hi) << 16);
}

// ---------------------------------------------------------------------------
// Pre-swizzle W1/W2 into MFMA B-fragment lane order (bf16). 44 blocks so the
// prologue is parallel, not one latency-bound CU.
// B-frag (16x16x32): lane holds B^T[n=lane&15][k=(lane>>4)*8+j], j=0..7.
// ---------------------------------------------------------------------------
__global__ __launch_bounds__(256) void wcvt_k(const float* __restrict__ W1,
                                              const float* __restrict__ W2,
                                              unsigned short* __restrict__ w1s,
                                              unsigned short* __restrict__ w2s) {
  int t = blockIdx.x * 256 + threadIdx.x;
  int T = gridDim.x * 256;
  for (int i = t; i < 8192; i += T) {
    int f = i >> 9, r = i & 511;
    int lane = r >> 3, j = r & 7;
    int ct = f >> 2, ks = f & 3;
    int n = ct * 16 + (lane & 15);
    int k = ks * 32 + (lane >> 4) * 8 + j;
    w1s[i] = f2bf(W1[k * F_HID + n]);
  }
  for (int i = t; i < 3072; i += T) {
    int f = i >> 9, r = i & 511;
    int lane = r >> 3, j = r & 7;
    int ct = f >> 1, ks = f & 1;
    int n = ct * 16 + (lane & 15);
    int k = ks * 32 + (lane >> 4) * 8 + j;
    w2s[i] = (n < F_OUT) ? f2bf(W2[k * F_OUT + n]) : (unsigned short)0;
  }
}

// ---------------------------------------------------------------------------
// FRONT (fused): blocks [0,NBLK) run pcount; blocks [NBLK,+gemmBlks) run
// MFMA GEMM1 on CUs pcount can't fill.
// ---------------------------------------------------------------------------
__global__ __launch_bounds__(256) void front_k(const float* __restrict__ x,
                                               const float* __restrict__ W1,
                                               const unsigned short* __restrict__ w1s,
                                               unsigned short* __restrict__ xw, int N,
                                               const int* __restrict__ ei,
                                               int* __restrict__ counts,
                                               int E, int NBLK, int NBUCK) {
  __shared__ int lh[NBMAX];
  if ((int)blockIdx.x < NBLK) {
    // ---- pcount ----
    int t = threadIdx.x, blk = blockIdx.x;
    lh[t] = 0;
    __syncthreads();
    int e0 = blk * CHUNK;
    int n = min(CHUNK, E - e0);
    for (int i = t; i < n; i += 256)
      atomicAdd(&lh[((unsigned)ei[E + e0 + i]) >> BSH], 1);
    __syncthreads();
    if (t < NBUCK) counts[t * NBLK + blk] = lh[t];
    return;
  }
  // ---- gemm1 ----
  int gblk = blockIdx.x - NBLK;
  int lane = threadIdx.x & 63;
  int wid  = gblk * 4 + (threadIdx.x >> 6);
  int row0 = wid * 16;
  if (row0 >= N) return;
  int m = lane & 15, q = lane >> 4;

  if (row0 + 16 <= N) {
    short8 b[16];
#pragma unroll
    for (int f = 0; f < 16; ++f)
      b[f] = *(const short8*)(w1s + f * 512 + lane * 8);

    short8 a[4];
#pragma unroll
    for (int ks = 0; ks < 4; ++ks) {
      const float* xp = x + (size_t)(row0 + m) * F_IN + ks * 32 + q * 8;
      float4 v0 = *(const float4*)xp;
      float4 v1 = *(const float4*)(xp + 4);
      short8 t;
      t[0] = (short)f2bf(v0.x); t[1] = (short)f2bf(v0.y);
      t[2] = (short)f2bf(v0.z); t[3] = (short)f2bf(v0.w);
      t[4] = (short)f2bf(v1.x); t[5] = (short)f2bf(v1.y);
      t[6] = (short)f2bf(v1.z); t[7] = (short)f2bf(v1.w);
      a[ks] = t;
    }

    f32x4 z = {0.f, 0.f, 0.f, 0.f};
    f32x4 acc[4] = {z, z, z, z};
#pragma unroll
    for (int ct = 0; ct < 4; ++ct)
#pragma unroll
      for (int ks = 0; ks < 4; ++ks)
        acc[ct] = __builtin_amdgcn_mfma_f32_16x16x32_bf16(a[ks], b[ct * 4 + ks],
                                                          acc[ct], 0, 0, 0);
#pragma unroll
    for (int ct = 0; ct < 4; ++ct)
#pragma unroll
      for (int r = 0; r < 4; ++r) {
        int row = row0 + q * 4 + r;                 // D: col=lane&15, row=q*4+reg
        xw[(size_t)row * F_HID + ct * 16 + m] = f2bf(acc[ct][r]);
      }
  } else {
    for (int r = 0; r < 16 && row0 + r < N; ++r) { // tail: col = lane
      const float* xr = x + (size_t)(row0 + r) * F_IN;
      float s = 0.f;
      for (int k = 0; k < F_IN; ++k) s = fmaf(xr[k], W1[k * F_HID + lane], s);
      xw[(size_t)(row0 + r) * F_HID + lane] = f2bf(s);
    }
  }
}

// ---------------------------------------------------------------------------
// Scan step A: per-2048-chunk totals of counts[0..M-1] -> psum[chunk].
// ---------------------------------------------------------------------------
__global__ __launch_bounds__(256) void scanA_k(const int* __restrict__ a,
                                               int* __restrict__ psum, int M) {
  int t = threadIdx.x;
  int base = blockIdx.x * 2048 + t * 8;
  int s = 0;
#pragma unroll
  for (int j = 0; j < 8; ++j) if (base + j < M) s += a[base + j];
#pragma unroll
  for (int off = 32; off; off >>= 1) s += __shfl_xor(s, off, 64);
  __shared__ int sm[4];
  if ((t & 63) == 0) sm[t >> 6] = s;
  __syncthreads();
  if (t == 0) psum[blockIdx.x] = sm[0] + sm[1] + sm[2] + sm[3];
}

// ---------------------------------------------------------------------------
// Scan step C: each block redundantly scans psum[0..nb) in LDS (nb <= 256),
// then scans its own 2048 chunk. Replaces the old scanB launch.
// ---------------------------------------------------------------------------
__global__ __launch_bounds__(256) void scanC_k(int* __restrict__ a,
                                               const int* __restrict__ psum,
                                               int M, int E, int nb) {
  __shared__ int sb[256];
  __shared__ int sm[256];
  int t = threadIdx.x;

  // redundant exclusive scan of the nb block totals
  int pv = (t < nb) ? psum[t] : 0;
  sb[t] = pv;
  __syncthreads();
  for (int off = 1; off < 256; off <<= 1) {
    int add = (t >= off) ? sb[t - off] : 0;
    __syncthreads();
    sb[t] += add;
    __syncthreads();
  }
  int excl = sb[t] - pv;
  __syncthreads();
  sb[t] = excl;
  __syncthreads();
  int blockBase = sb[blockIdx.x];

  int base = blockIdx.x * 2048 + t * 8;
  int v[8];
  int s = 0;
#pragma unroll
  for (int j = 0; j < 8; ++j) {
    v[j] = (base + j < M) ? a[base + j] : 0;
    s += v[j];
  }
  sm[t] = s;
  __syncthreads();
  for (int off = 1; off < 256; off <<= 1) {
    int add = (t >= off) ? sm[t - off] : 0;
    __syncthreads();
    sm[t] += add;
    __syncthreads();
  }
  int run = blockBase + sm[t] - s;
#pragma unroll
  for (int j = 0; j < 8; ++j) {
    if (base + j < M) a[base + j] = run;
    run += v[j];
  }
  if (blockIdx.x == 0 && t == 0) a[M] = E;   // sentinel
}

// ---------------------------------------------------------------------------
// Multisplit P2: stable partition into bucket-major ebuf.
// ebuf entries are packed u32: (dst & 511) << 17 | src  (src < 131072).
// ---------------------------------------------------------------------------
__global__ __launch_bounds__(256) void partition_k(const int* __restrict__ bases,
                                                   const int* __restrict__ ei,
                                                   unsigned* __restrict__ ebuf,
                                                   int E, int NBLK, int NBUCK) {
  __shared__ uint2 slots[CHUNK];          // 32 KB
  __shared__ int scn[NBMAX], lcur[NBMAX], gadj[NBMAX];
  int t = threadIdx.x, blk = blockIdx.x;
  int e0 = blk * CHUNK;
  int n = min(CHUNK, E - e0);

  int i0 = t * NBLK + blk;
  int cnt = 0, base0 = 0;
  if (t < NBUCK) {
    base0 = bases[i0];
    cnt = bases[i0 + 1] - base0;
  }
  scn[t] = cnt;
  __syncthreads();
  for (int off = 1; off < 256; off <<= 1) {
    int add = (t >= off) ? scn[t - off] : 0;
    __syncthreads();
    scn[t] += add;
    __syncthreads();
  }
  int excl = scn[t] - cnt;
  if (t < NBUCK) { lcur[t] = excl; gadj[t] = base0 - excl; }
  __syncthreads();

  for (int i = t; i < n; i += 256) {
    int s = ei[e0 + i], d = ei[E + e0 + i];
    int pos = atomicAdd(&lcur[((unsigned)d) >> BSH], 1);
    slots[pos] = make_uint2((unsigned)s, (unsigned)d);
  }
  __syncthreads();
  for (int i = t; i < n; i += 256) {
    uint2 sd = slots[i];
    unsigned pk = ((sd.y & 511u) << 17) | sd.x;
    ebuf[gadj[sd.y >> BSH] + i] = pk;
  }
}

// ---------------------------------------------------------------------------
// Bucket-local CSR build: LDS-stage the bucket's packed edges (read once),
// LDS histogram + scan -> row_ptr; LDS cursor fill. 512 threads: only
// NBUCK (~196) blocks exist, so per-block wave count carries latency hiding.
// ---------------------------------------------------------------------------
__global__ __launch_bounds__(BLD_T) void build_k(const unsigned* __restrict__ ebuf,
                                                 const int* __restrict__ bases,
                                                 int* __restrict__ row_ptr,
                                                 int* __restrict__ csr,
                                                 int N, int E, int NBLK) {
  __shared__ int hist[512];
  __shared__ int psc[256];
  __shared__ unsigned stg[BLD_CAP];       // 40 KB
  int t = threadIdx.x, b = blockIdx.x;
  int nodeBase = b << BSH;
  int S = bases[b * NBLK];
  int T = bases[(b + 1) * NBLK];
  int n = T - S;
  bool useLds = (n <= BLD_CAP);

  if (t < 512) hist[t] = 0;
  __syncthreads();
  for (int i = t; i < n; i += BLD_T) {
    unsigned v = ebuf[S + i];
    if (useLds) stg[i] = v;
    atomicAdd(&hist[v >> 17], 1);
  }
  __syncthreads();

  int v0 = 0, v1 = 0, pair = 0;
  if (t < 256) {
    v0 = hist[2 * t]; v1 = hist[2 * t + 1];
    pair = v0 + v1;
    psc[t] = pair;
  }
  __syncthreads();
  for (int off = 1; off < 256; off <<= 1) {
    int add = (t >= off && t < 256) ? psc[t - off] : 0;
    __syncthreads();
    if (t < 256) psc[t] += add;
    __syncthreads();
  }
  if (t < 256) {
    int ep = psc[t] - pair;
    int e0 = ep, e1 = ep + v0;
    int node0 = nodeBase + 2 * t;
    if (node0 < N) row_ptr[node0] = S + e0;
    if (node0 + 1 < N) row_ptr[node0 + 1] = S + e1;
    hist[2 * t] = e0; hist[2 * t + 1] = e1;   // reuse as cursors
  }
  if (b == 0 && t == 0) row_ptr[N] = E;
  __syncthreads();
  for (int i = t; i < n; i += BLD_T) {
    unsigned v = useLds ? stg[i] : ebuf[S + i];
    int pos = atomicAdd(&hist[v >> 17], 1);
    csr[S + pos] = (int)(v & 0x1FFFFu);
  }
}

// ---------------------------------------------------------------------------
// FUSED aggregation-1 + bias1 + ReLU + GEMM2.
// Wave = 8 rows (lane: row=lane>>3, part=lane&7 owning 8 cols = 16 B), block
// = 4 waves = 32 rows. After aggregation, h[32][64] (bf16, packed uint4) is
// staged in LDS with an XOR part-swizzle; waves 0/1 then run the 64x40 MFMA
// GEMM for rows [0,16) / [16,32) and write hw[N][40] bf16 (80-B rows).
// Eliminates the global h buffer and shrinks the layer-2 gather to 40 cols.
// ---------------------------------------------------------------------------
__global__ __launch_bounds__(256) void agg1g2_k(const unsigned short* __restrict__ xw,
                                                const int* __restrict__ row_ptr,
                                                const int* __restrict__ csr,
                                                const float* __restrict__ b1,
                                                const unsigned short* __restrict__ w2s,
                                                const float* __restrict__ W2,
                                                unsigned short* __restrict__ hw, int N) {
  __shared__ uint4 hsm[32][8];            // 4 KB, XOR-swizzled on part
  int t = threadIdx.x;
  int wave = t >> 6, lane = t & 63;
  int blockRow0 = blockIdx.x * 32;
  int rowBase = blockRow0 + wave * 8;
  int row = rowBase + (lane >> 3);
  int part = lane & 7;
  bool live = row < N;

  int start = live ? row_ptr[row] : 0;
  int end   = live ? row_ptr[row + 1] : 0;

  float acc[8], bcc[8];
#pragma unroll
  for (int j = 0; j < 8; ++j) { acc[j] = 0.f; bcc[j] = 0.f; }

  int i = start;
  for (; i + 1 < end; i += 2) {
    int s0 = csr[i];
    int s1 = csr[i + 1];
    uint4 v0 = *(const uint4*)(xw + ((size_t)s0 << 6) + (part << 3));
    uint4 v1 = *(const uint4*)(xw + ((size_t)s1 << 6) + (part << 3));
    acc[0] += bflo(v0.x); acc[1] += bfhi(v0.x);
    acc[2] += bflo(v0.y); acc[3] += bfhi(v0.y);
    acc[4] += bflo(v0.z); acc[5] += bfhi(v0.z);
    acc[6] += bflo(v0.w); acc[7] += bfhi(v0.w);
    bcc[0] += bflo(v1.x); bcc[1] += bfhi(v1.x);
    bcc[2] += bflo(v1.y); bcc[3] += bfhi(v1.y);
    bcc[4] += bflo(v1.z); bcc[5] += bfhi(v1.z);
    bcc[6] += bflo(v1.w); bcc[7] += bfhi(v1.w);
  }
  if (i < end) {
    int s = csr[i];
    uint4 v = *(const uint4*)(xw + ((size_t)s << 6) + (part << 3));
    acc[0] += bflo(v.x); acc[1] += bfhi(v.x);
    acc[2] += bflo(v.y); acc[3] += bfhi(v.y);
    acc[4] += bflo(v.z); acc[5] += bfhi(v.z);
    acc[6] += bflo(v.w); acc[7] += bfhi(v.w);
  }

  if (live) {
    int c0 = part << 3;
    float4 bA = *(const float4*)(b1 + c0);
    float4 bB = *(const float4*)(b1 + c0 + 4);
    float r0 = fmaxf(acc[0] + bcc[0] + bA.x, 0.f);
    float r1 = fmaxf(acc[1] + bcc[1] + bA.y, 0.f);
    float r2 = fmaxf(acc[2] + bcc[2] + bA.z, 0.f);
    float r3 = fmaxf(acc[3] + bcc[3] + bA.w, 0.f);
    float r4 = fmaxf(acc[4] + bcc[4] + bB.x, 0.f);
    float r5 = fmaxf(acc[5] + bcc[5] + bB.y, 0.f);
    float r6 = fmaxf(acc[6] + bcc[6] + bB.z, 0.f);
    float r7 = fmaxf(acc[7] + bcc[7] + bB.w, 0.f);
    uint4 o = make_uint4(packbf(r0, r1), packbf(r2, r3), packbf(r4, r5), packbf(r6, r7));
    int lr = row - blockRow0;
    hsm[lr][part ^ (lr & 7)] = o;
  }
  __syncthreads();

  // ---- GEMM2: h[32][64] @ W2[64][40] -> hw rows (bf16) ----
  if (wave < 2) {
    int frow0 = blockRow0 + wave * 16;
    if (frow0 >= N) return;
    int m = lane & 15, q = lane >> 4;
    if (frow0 + 16 <= N) {
      short8 b[6];
#pragma unroll
      for (int f = 0; f < 6; ++f)
        b[f] = *(const short8*)(w2s + f * 512 + lane * 8);
      short8 a[2];
#pragma unroll
      for (int ks = 0; ks < 2; ++ks) {
        int lr = wave * 16 + m;
        int p = ks * 4 + q;
        a[ks] = *(const short8*)&hsm[lr][p ^ (lr & 7)];
      }
      f32x4 z = {0.f, 0.f, 0.f, 0.f};
      f32x4 acc2[3] = {z, z, z};
#pragma unroll
      for (int ct = 0; ct < 3; ++ct)
#pragma unroll
        for (int ks = 0; ks < 2; ++ks)
          acc2[ct] = __builtin_amdgcn_mfma_f32_16x16x32_bf16(a[ks], b[ct * 2 + ks],
                                                             acc2[ct], 0, 0, 0);
#pragma unroll
      for (int ct = 0; ct < 3; ++ct)
#pragma unroll
        for (int r = 0; r < 4; ++r) {
          int row2 = frow0 + q * 4 + r;
          int c = ct * 16 + m;
          if (c < F_OUT) hw[(size_t)row2 * F_OUT + c] = f2bf(acc2[ct][r]);
        }
    } else {
      // tail rows: scalar from swizzled LDS
      for (int r = 0; r < 16; ++r) {
        int row2 = frow0 + r;
        if (row2 >= N) break;
        if (lane < F_OUT) {
          int lr = wave * 16 + r;
          float s = 0.f;
          for (int k = 0; k < F_HID; ++k) {
            const unsigned short* hp =
                (const unsigned short*)&hsm[lr][(k >> 3) ^ (lr & 7)];
            s = fmaf(bf2f(hp[k & 7]), W2[k * F_OUT + lane], s);
          }
          hw[(size_t)row2 * F_OUT + lane] = f2bf(s);
        }
      }
    }
  }
}

// ---------------------------------------------------------------------------
// Aggregation layer 2 + bias2 + log_softmax. hw rows are 40 bf16 (80 B);
// parts 0..4 carry data, parts 5..7 idle on loads. Softmax reduces over the
// low-3 lane bits (parts 0..4 hold cols 0..39).
// ---------------------------------------------------------------------------
__global__ __launch_bounds__(256) void agg2_ls_k(const unsigned short* __restrict__ hw,
                                                 const int* __restrict__ row_ptr,
                                                 const int* __restrict__ csr,
                                                 const float* __restrict__ b2,
                                                 float* __restrict__ out, int N) {
  int wid = (blockIdx.x * 256 + threadIdx.x) >> 6;
  int lane = threadIdx.x & 63;
  int rowBase = wid * 8;
  if (rowBase >= N) return;
  int row = rowBase + (lane >> 3);
  int part = lane & 7;
  bool live = row < N;
  bool ld = live && (part < 5);

  int start = live ? row_ptr[row] : 0;
  int end   = live ? row_ptr[row + 1] : 0;

  float acc[8], bcc[8];
#pragma unroll
  for (int j = 0; j < 8; ++j) { acc[j] = 0.f; bcc[j] = 0.f; }

  int i = start;
  for (; i + 1 < end; i += 2) {
    int s0 = csr[i];
    int s1 = csr[i + 1];
    if (ld) {
      uint4 v0 = *(const uint4*)(hw + (size_t)s0 * F_OUT + (part << 3));
      uint4 v1 = *(const uint4*)(hw + (size_t)s1 * F_OUT + (part << 3));
      acc[0] += bflo(v0.x); acc[1] += bfhi(v0.x);
      acc[2] += bflo(v0.y); acc[3] += bfhi(v0.y);
      acc[4] += bflo(v0.z); acc[5] += bfhi(v0.z);
      acc[6] += bflo(v0.w); acc[7] += bfhi(v0.w);
      bcc[0] += bflo(v1.x); bcc[1] += bfhi(v1.x);
      bcc[2] += bflo(v1.y); bcc[3] += bfhi(v1.y);
      bcc[4] += bflo(v1.z); bcc[5] += bfhi(v1.z);
      bcc[6] += bflo(v1.w); bcc[7] += bfhi(v1.w);
    }
  }
  if (i < end && ld) {
    int s = csr[i];
    uint4 v = *(const uint4*)(hw + (size_t)s * F_OUT + (part << 3));
    acc[0] += bflo(v.x); acc[1] += bfhi(v.x);
    acc[2] += bflo(v.y); acc[3] += bfhi(v.y);
    acc[4] += bflo(v.z); acc[5] += bfhi(v.z);
    acc[6] += bflo(v.w); acc[7] += bfhi(v.w);
  }

  bool valid = ld;
  float vj[8];
  float m = -3.4e38f;
  if (valid) {
    int c0 = part << 3;
    float4 bA = *(const float4*)(b2 + c0);
    float4 bB = *(const float4*)(b2 + c0 + 4);
    vj[0] = acc[0] + bcc[0] + bA.x; vj[1] = acc[1] + bcc[1] + bA.y;
    vj[2] = acc[2] + bcc[2] + bA.z; vj[3] = acc[3] + bcc[3] + bA.w;
    vj[4] = acc[4] + bcc[4] + bB.x; vj[5] = acc[5] + bcc[5] + bB.y;
    vj[6] = acc[6] + bcc[6] + bB.z; vj[7] = acc[7] + bcc[7] + bB.w;
#pragma unroll
    for (int j = 0; j < 8; ++j) m = fmaxf(m, vj[j]);
  }
#pragma unroll
  for (int off = 1; off < 8; off <<= 1) m = fmaxf(m, __shfl_xor(m, off, 64));
  float ex = 0.f;
  if (valid) {
#pragma unroll
    for (int j = 0; j < 8; ++j) ex += __expf(vj[j] - m);
  }
#pragma unroll
  for (int off = 1; off < 8; off <<= 1) ex += __shfl_xor(ex, off, 64);
  float lse = __logf(ex) + m;

  if (valid) {
    int c0 = part << 3;
    float* op = out + (size_t)row * F_OUT + c0;
    *(float4*)op = make_float4(vj[0] - lse, vj[1] - lse, vj[2] - lse, vj[3] - lse);
    *(float4*)(op + 4) = make_float4(vj[4] - lse, vj[5] - lse, vj[6] - lse, vj[7] - lse);
  }
}

// ---------------------------------------------------------------------------
// ws layout (≈28 MB):
//   regA : xw[N,64] bf16
//   regB : ebuf[E] u32 — reused as hw[N,40] bf16 (ebuf dead after build_k)
//   row_ptr : N+1 | csr : E | counts : M+1 | psum : 256 | w1s : 8192 | w2s : 3072
// ---------------------------------------------------------------------------
extern "C" void kernel_launch(void* const* d_in, const int* in_sizes, int n_in,
                              void* d_out, int out_size, void* d_ws, size_t ws_size,
                              hipStream_t stream) {
  const float* x  = (const float*)d_in[0];
  const int*   ei = (const int*)d_in[1];
  const float* W1 = (const float*)d_in[2];
  const float* b1 = (const float*)d_in[3];
  const float* W2 = (const float*)d_in[4];
  const float* b2 = (const float*)d_in[5];

  int N = in_sizes[0] / F_IN;
  int E = in_sizes[1] / 2;

  char* base = (char*)d_ws;
  size_t szA = (size_t)N * F_HID * sizeof(unsigned short);
  size_t szEb = (size_t)E * sizeof(unsigned);
  size_t szHw = (size_t)N * F_OUT * sizeof(unsigned short);
  size_t szB = (szEb > szHw) ? szEb : szHw;
  unsigned short* xw = (unsigned short*)base;
  char* regB = base + ((szA + 255) & ~(size_t)255);
  unsigned* ebuf       = (unsigned*)regB;
  unsigned short* hw   = (unsigned short*)regB;
  int* row_ptr = (int*)(regB + ((szB + 255) & ~(size_t)255));
  int* csr     = row_ptr + N + 1;
  int* counts  = csr + E;
  float* out = (float*)d_out;

  int aggGrid  = (N * 8 + 255) / 256;      // 8 threads per row
  int gemmGrid = (N + 63) / 64;            // 4 waves x 16 rows per block
  int fusGrid  = (N + 31) / 32;            // 32 rows per block (agg1+gemm2)
  int NBLK  = (E + CHUNK - 1) / CHUNK;
  int NBUCK = (N + 511) >> BSH;
  int M = NBUCK * NBLK;
  int* psum = counts + M + 1;
  unsigned short* w1s = (unsigned short*)(psum + 256);
  unsigned short* w2s = w1s + 8192;
  int scanBlocks = (M + 2047) / 2048;

  wcvt_k<<<44, 256, 0, stream>>>(W1, W2, w1s, w2s);

  // fused: pcount (blocks 0..NBLK-1) + gemm1 (remaining blocks)
  front_k<<<NBLK + gemmGrid, 256, 0, stream>>>(x, W1, w1s, xw, N,
                                               ei, counts, E, NBLK, NBUCK);

  scanA_k<<<scanBlocks, 256, 0, stream>>>(counts, psum, M);
  scanC_k<<<scanBlocks, 256, 0, stream>>>(counts, psum, M, E, scanBlocks);
  partition_k<<<NBLK, 256, 0, stream>>>(counts, ei, ebuf, E, NBLK, NBUCK);
  build_k<<<NBUCK, BLD_T, 0, stream>>>(ebuf, counts, row_ptr, csr, N, E, NBLK);

  agg1g2_k<<<fusGrid, 256, 0, stream>>>(xw, row_ptr, csr, b1, w2s, W2, hw, N);
  agg2_ls_k<<<aggGrid, 256, 0, stream>>>(hw, row_ptr, csr, b2, out, N);
}

// Round 2
// 218.371 us; speedup vs baseline: 1.0450x; 1.0002x over previous
//
#include <hip/hip_runtime.h>
#include <cstdint>
#include <cstddef>

#define F_IN  128
#define F_HID 64
#define F_OUT 40

#define BSH   9     // bucket = dst >> 9 (512 nodes/bucket)
#define NBMAX 256   // supports N <= 131072
#define CHUNK 4096  // edges per partition block

#define BLD_T   512   // build_k threads
#define BLD_CAP 10240 // LDS-staged edges per bucket (40 KB)

typedef __attribute__((ext_vector_type(8))) short short8;   // 8 bf16 = 4 VGPR
typedef __attribute__((ext_vector_type(4))) float f32x4;    // MFMA C/D

// bf16 <-> f32 helpers (RNE on pack; values are finite)
__device__ __forceinline__ unsigned short f2bf(float f) {
  unsigned u = __float_as_uint(f);
  u += 0x7fffu + ((u >> 16) & 1u);
  return (unsigned short)(u >> 16);
}
__device__ __forceinline__ float bf2f(unsigned short b) {
  return __uint_as_float((unsigned)b << 16);
}
__device__ __forceinline__ float bflo(unsigned u) { return __uint_as_float(u << 16); }
__device__ __forceinline__ float bfhi(unsigned u) { return __uint_as_float(u & 0xffff0000u); }
__device__ __forceinline__ unsigned packbf(float lo, float hi) {
  return (unsigned)f2bf(lo) | ((unsigned)f2bf(hi) << 16);
}

// ---------------------------------------------------------------------------
// FRONT (fused): blocks [0,NBLK) run pcount (block 0 additionally emits the
// w2s MFMA-swizzled copy of W2 for the later GEMM2); blocks [NBLK,+gemmBlks)
// run MFMA GEMM1, each converting W1 into a 16 KB LDS B-fragment copy first
// (removes the former wcvt_k kernel + its launch gap).
// B-frag (16x16x32): lane holds B^T[n=lane&15][k=(lane>>4)*8+j], j=0..7.
// ---------------------------------------------------------------------------
__global__ __launch_bounds__(256) void front_k(const float* __restrict__ x,
                                               const float* __restrict__ W1,
                                               const float* __restrict__ W2,
                                               unsigned short* __restrict__ w2s,
                                               unsigned short* __restrict__ xw, int N,
                                               const int* __restrict__ ei,
                                               int* __restrict__ counts,
                                               int E, int NBLK, int NBUCK) {
  __shared__ int lh[NBMAX];
  __shared__ unsigned short w1l[8192];    // 16 KB swizzled W1 (gemm1 branch)
  int t = threadIdx.x;

  if ((int)blockIdx.x < NBLK) {
    // ---- pcount ----
    int blk = blockIdx.x;
    lh[t] = 0;
    __syncthreads();
    int e0 = blk * CHUNK;
    int n = min(CHUNK, E - e0);
    for (int i = t; i < n; i += 256)
      atomicAdd(&lh[((unsigned)ei[E + e0 + i]) >> BSH], 1);
    __syncthreads();
    if (t < NBUCK) counts[t * NBLK + blk] = lh[t];
    if (blk == 0) {
      // emit swizzled W2 (zero-padded cols 40..47) for GEMM2
      for (int i = t; i < 3072; i += 256) {
        int f = i >> 9, r = i & 511;
        int lane = r >> 3, j = r & 7;
        int ct = f >> 1, ks = f & 1;
        int n2 = ct * 16 + (lane & 15);
        int k = ks * 32 + (lane >> 4) * 8 + j;
        w2s[i] = (n2 < F_OUT) ? f2bf(W2[k * F_OUT + n2]) : (unsigned short)0;
      }
    }
    return;
  }

  // ---- gemm1: convert W1 -> LDS (all threads, coalesced global reads) ----
  {
    int k = t >> 1, n0 = (t & 1) * 32;       // thread owns W1[k][n0..n0+32)
    const float4* wp = (const float4*)(W1 + k * F_HID + n0);
    float4 v[8];
#pragma unroll
    for (int u = 0; u < 8; ++u) v[u] = wp[u];
#pragma unroll
    for (int u = 0; u < 32; ++u) {
      int n = n0 + u;
      float f = ((const float*)v)[u];
      int idx = ((n >> 4) * 4 + (k >> 5)) * 512 +
                (((k >> 3) & 3) * 16 + (n & 15)) * 8 + (k & 7);
      w1l[idx] = f2bf(f);
    }
  }
  __syncthreads();

  int gblk = blockIdx.x - NBLK;
  int lane = t & 63;
  int wid  = gblk * 4 + (t >> 6);
  int row0 = wid * 16;
  if (row0 >= N) return;
  int m = lane & 15, q = lane >> 4;

  if (row0 + 16 <= N) {
    short8 b[16];
#pragma unroll
    for (int f = 0; f < 16; ++f)
      b[f] = *(const short8*)(w1l + f * 512 + lane * 8);

    short8 a[4];
#pragma unroll
    for (int ks = 0; ks < 4; ++ks) {
      const float* xp = x + (size_t)(row0 + m) * F_IN + ks * 32 + q * 8;
      float4 v0 = *(const float4*)xp;
      float4 v1 = *(const float4*)(xp + 4);
      short8 tt;
      tt[0] = (short)f2bf(v0.x); tt[1] = (short)f2bf(v0.y);
      tt[2] = (short)f2bf(v0.z); tt[3] = (short)f2bf(v0.w);
      tt[4] = (short)f2bf(v1.x); tt[5] = (short)f2bf(v1.y);
      tt[6] = (short)f2bf(v1.z); tt[7] = (short)f2bf(v1.w);
      a[ks] = tt;
    }

    f32x4 z = {0.f, 0.f, 0.f, 0.f};
    f32x4 acc[4] = {z, z, z, z};
#pragma unroll
    for (int ct = 0; ct < 4; ++ct)
#pragma unroll
      for (int ks = 0; ks < 4; ++ks)
        acc[ct] = __builtin_amdgcn_mfma_f32_16x16x32_bf16(a[ks], b[ct * 4 + ks],
                                                          acc[ct], 0, 0, 0);
#pragma unroll
    for (int ct = 0; ct < 4; ++ct)
#pragma unroll
      for (int r = 0; r < 4; ++r) {
        int row = row0 + q * 4 + r;                 // D: col=lane&15, row=q*4+reg
        xw[(size_t)row * F_HID + ct * 16 + m] = f2bf(acc[ct][r]);
      }
  } else {
    for (int r = 0; r < 16 && row0 + r < N; ++r) { // tail: col = lane
      const float* xr = x + (size_t)(row0 + r) * F_IN;
      float s = 0.f;
      for (int k = 0; k < F_IN; ++k) s = fmaf(xr[k], W1[k * F_HID + lane], s);
      xw[(size_t)(row0 + r) * F_HID + lane] = f2bf(s);
    }
  }
}

// ---------------------------------------------------------------------------
// Scan step A: per-2048-chunk totals of counts[0..M-1] -> psum[chunk].
// ---------------------------------------------------------------------------
__global__ __launch_bounds__(256) void scanA_k(const int* __restrict__ a,
                                               int* __restrict__ psum, int M) {
  int t = threadIdx.x;
  int base = blockIdx.x * 2048 + t * 8;
  int s = 0;
#pragma unroll
  for (int j = 0; j < 8; ++j) if (base + j < M) s += a[base + j];
#pragma unroll
  for (int off = 32; off; off >>= 1) s += __shfl_xor(s, off, 64);
  __shared__ int sm[4];
  if ((t & 63) == 0) sm[t >> 6] = s;
  __syncthreads();
  if (t == 0) psum[blockIdx.x] = sm[0] + sm[1] + sm[2] + sm[3];
}

// ---------------------------------------------------------------------------
// Scan step C: each block redundantly scans psum[0..nb) in LDS (nb <= 256),
// then scans its own 2048 chunk.
// ---------------------------------------------------------------------------
__global__ __launch_bounds__(256) void scanC_k(int* __restrict__ a,
                                               const int* __restrict__ psum,
                                               int M, int E, int nb) {
  __shared__ int sb[256];
  __shared__ int sm[256];
  int t = threadIdx.x;

  int pv = (t < nb) ? psum[t] : 0;
  sb[t] = pv;
  __syncthreads();
  for (int off = 1; off < 256; off <<= 1) {
    int add = (t >= off) ? sb[t - off] : 0;
    __syncthreads();
    sb[t] += add;
    __syncthreads();
  }
  int excl = sb[t] - pv;
  __syncthreads();
  sb[t] = excl;
  __syncthreads();
  int blockBase = sb[blockIdx.x];

  int base = blockIdx.x * 2048 + t * 8;
  int v[8];
  int s = 0;
#pragma unroll
  for (int j = 0; j < 8; ++j) {
    v[j] = (base + j < M) ? a[base + j] : 0;
    s += v[j];
  }
  sm[t] = s;
  __syncthreads();
  for (int off = 1; off < 256; off <<= 1) {
    int add = (t >= off) ? sm[t - off] : 0;
    __syncthreads();
    sm[t] += add;
    __syncthreads();
  }
  int run = blockBase + sm[t] - s;
#pragma unroll
  for (int j = 0; j < 8; ++j) {
    if (base + j < M) a[base + j] = run;
    run += v[j];
  }
  if (blockIdx.x == 0 && t == 0) a[M] = E;   // sentinel
}

// ---------------------------------------------------------------------------
// Multisplit P2: stable partition into bucket-major ebuf.
// ebuf entries are packed u32: (dst & 511) << 17 | src  (src < 131072).
// ---------------------------------------------------------------------------
__global__ __launch_bounds__(256) void partition_k(const int* __restrict__ bases,
                                                   const int* __restrict__ ei,
                                                   unsigned* __restrict__ ebuf,
                                                   int E, int NBLK, int NBUCK) {
  __shared__ uint2 slots[CHUNK];          // 32 KB
  __shared__ int scn[NBMAX], lcur[NBMAX], gadj[NBMAX];
  int t = threadIdx.x, blk = blockIdx.x;
  int e0 = blk * CHUNK;
  int n = min(CHUNK, E - e0);

  int i0 = t * NBLK + blk;
  int cnt = 0, base0 = 0;
  if (t < NBUCK) {
    base0 = bases[i0];
    cnt = bases[i0 + 1] - base0;
  }
  scn[t] = cnt;
  __syncthreads();
  for (int off = 1; off < 256; off <<= 1) {
    int add = (t >= off) ? scn[t - off] : 0;
    __syncthreads();
    scn[t] += add;
    __syncthreads();
  }
  int excl = scn[t] - cnt;
  if (t < NBUCK) { lcur[t] = excl; gadj[t] = base0 - excl; }
  __syncthreads();

  for (int i = t; i < n; i += 256) {
    int s = ei[e0 + i], d = ei[E + e0 + i];
    int pos = atomicAdd(&lcur[((unsigned)d) >> BSH], 1);
    slots[pos] = make_uint2((unsigned)s, (unsigned)d);
  }
  __syncthreads();
  for (int i = t; i < n; i += 256) {
    uint2 sd = slots[i];
    unsigned pk = ((sd.y & 511u) << 17) | sd.x;
    ebuf[gadj[sd.y >> BSH] + i] = pk;
  }
}

// ---------------------------------------------------------------------------
// Bucket-local CSR build: LDS-stage the bucket's packed edges (read once),
// LDS histogram + scan -> row_ptr; LDS cursor fill.
// ---------------------------------------------------------------------------
__global__ __launch_bounds__(BLD_T) void build_k(const unsigned* __restrict__ ebuf,
                                                 const int* __restrict__ bases,
                                                 int* __restrict__ row_ptr,
                                                 int* __restrict__ csr,
                                                 int N, int E, int NBLK) {
  __shared__ int hist[512];
  __shared__ int psc[256];
  __shared__ unsigned stg[BLD_CAP];       // 40 KB
  int t = threadIdx.x, b = blockIdx.x;
  int nodeBase = b << BSH;
  int S = bases[b * NBLK];
  int T = bases[(b + 1) * NBLK];
  int n = T - S;
  bool useLds = (n <= BLD_CAP);

  if (t < 512) hist[t] = 0;
  __syncthreads();
  for (int i = t; i < n; i += BLD_T) {
    unsigned v = ebuf[S + i];
    if (useLds) stg[i] = v;
    atomicAdd(&hist[v >> 17], 1);
  }
  __syncthreads();

  int v0 = 0, v1 = 0, pair = 0;
  if (t < 256) {
    v0 = hist[2 * t]; v1 = hist[2 * t + 1];
    pair = v0 + v1;
    psc[t] = pair;
  }
  __syncthreads();
  for (int off = 1; off < 256; off <<= 1) {
    int add = (t >= off && t < 256) ? psc[t - off] : 0;
    __syncthreads();
    if (t < 256) psc[t] += add;
    __syncthreads();
  }
  if (t < 256) {
    int ep = psc[t] - pair;
    int e0 = ep, e1 = ep + v0;
    int node0 = nodeBase + 2 * t;
    if (node0 < N) row_ptr[node0] = S + e0;
    if (node0 + 1 < N) row_ptr[node0 + 1] = S + e1;
    hist[2 * t] = e0; hist[2 * t + 1] = e1;   // reuse as cursors
  }
  if (b == 0 && t == 0) row_ptr[N] = E;
  __syncthreads();
  for (int i = t; i < n; i += BLD_T) {
    unsigned v = useLds ? stg[i] : ebuf[S + i];
    int pos = atomicAdd(&hist[v >> 17], 1);
    csr[S + pos] = (int)(v & 0x1FFFFu);
  }
}

// ---------------------------------------------------------------------------
// FUSED aggregation-1 + bias1 + ReLU + GEMM2.
// Wave = 8 rows (lane: row=lane>>3, part=lane&7 owning 8 cols = 16 B).
// Gather loop unrolled 4-wide: 4 independent dwordx4 gathers in flight per
// lane before the accumulate chain waits (latency-bound gather -> MLP).
// After aggregation, h[32][64] staged in XOR-swizzled LDS; waves 0/1 run the
// 64x40 MFMA GEMM and write hw[N][40] bf16.
// ---------------------------------------------------------------------------
__global__ __launch_bounds__(256) void agg1g2_k(const unsigned short* __restrict__ xw,
                                                const int* __restrict__ row_ptr,
                                                const int* __restrict__ csr,
                                                const float* __restrict__ b1,
                                                const unsigned short* __restrict__ w2s,
                                                const float* __restrict__ W2,
                                                unsigned short* __restrict__ hw, int N) {
  __shared__ uint4 hsm[32][8];            // 4 KB, XOR-swizzled on part
  int t = threadIdx.x;
  int wave = t >> 6, lane = t & 63;
  int blockRow0 = blockIdx.x * 32;
  int rowBase = blockRow0 + wave * 8;
  int row = rowBase + (lane >> 3);
  int part = lane & 7;
  bool live = row < N;

  int start = live ? row_ptr[row] : 0;
  int end   = live ? row_ptr[row + 1] : 0;

  float acc[8], bcc[8];
#pragma unroll
  for (int j = 0; j < 8; ++j) { acc[j] = 0.f; bcc[j] = 0.f; }

  int i = start;
  for (; i + 3 < end; i += 4) {
    int s0 = csr[i];
    int s1 = csr[i + 1];
    int s2 = csr[i + 2];
    int s3 = csr[i + 3];
    uint4 v0 = *(const uint4*)(xw + ((size_t)s0 << 6) + (part << 3));
    uint4 v1 = *(const uint4*)(xw + ((size_t)s1 << 6) + (part << 3));
    uint4 v2 = *(const uint4*)(xw + ((size_t)s2 << 6) + (part << 3));
    uint4 v3 = *(const uint4*)(xw + ((size_t)s3 << 6) + (part << 3));
    acc[0] += bflo(v0.x); acc[1] += bfhi(v0.x);
    acc[2] += bflo(v0.y); acc[3] += bfhi(v0.y);
    acc[4] += bflo(v0.z); acc[5] += bfhi(v0.z);
    acc[6] += bflo(v0.w); acc[7] += bfhi(v0.w);
    bcc[0] += bflo(v1.x); bcc[1] += bfhi(v1.x);
    bcc[2] += bflo(v1.y); bcc[3] += bfhi(v1.y);
    bcc[4] += bflo(v1.z); bcc[5] += bfhi(v1.z);
    bcc[6] += bflo(v1.w); bcc[7] += bfhi(v1.w);
    acc[0] += bflo(v2.x); acc[1] += bfhi(v2.x);
    acc[2] += bflo(v2.y); acc[3] += bfhi(v2.y);
    acc[4] += bflo(v2.z); acc[5] += bfhi(v2.z);
    acc[6] += bflo(v2.w); acc[7] += bfhi(v2.w);
    bcc[0] += bflo(v3.x); bcc[1] += bfhi(v3.x);
    bcc[2] += bflo(v3.y); bcc[3] += bfhi(v3.y);
    bcc[4] += bflo(v3.z); bcc[5] += bfhi(v3.z);
    bcc[6] += bflo(v3.w); bcc[7] += bfhi(v3.w);
  }
  for (; i < end; ++i) {
    int s = csr[i];
    uint4 v = *(const uint4*)(xw + ((size_t)s << 6) + (part << 3));
    acc[0] += bflo(v.x); acc[1] += bfhi(v.x);
    acc[2] += bflo(v.y); acc[3] += bfhi(v.y);
    acc[4] += bflo(v.z); acc[5] += bfhi(v.z);
    acc[6] += bflo(v.w); acc[7] += bfhi(v.w);
  }

  if (live) {
    int c0 = part << 3;
    float4 bA = *(const float4*)(b1 + c0);
    float4 bB = *(const float4*)(b1 + c0 + 4);
    float r0 = fmaxf(acc[0] + bcc[0] + bA.x, 0.f);
    float r1 = fmaxf(acc[1] + bcc[1] + bA.y, 0.f);
    float r2 = fmaxf(acc[2] + bcc[2] + bA.z, 0.f);
    float r3 = fmaxf(acc[3] + bcc[3] + bA.w, 0.f);
    float r4 = fmaxf(acc[4] + bcc[4] + bB.x, 0.f);
    float r5 = fmaxf(acc[5] + bcc[5] + bB.y, 0.f);
    float r6 = fmaxf(acc[6] + bcc[6] + bB.z, 0.f);
    float r7 = fmaxf(acc[7] + bcc[7] + bB.w, 0.f);
    uint4 o = make_uint4(packbf(r0, r1), packbf(r2, r3), packbf(r4, r5), packbf(r6, r7));
    int lr = row - blockRow0;
    hsm[lr][part ^ (lr & 7)] = o;
  }
  __syncthreads();

  // ---- GEMM2: h[32][64] @ W2[64][40] -> hw rows (bf16) ----
  if (wave < 2) {
    int frow0 = blockRow0 + wave * 16;
    if (frow0 >= N) return;
    int m = lane & 15, q = lane >> 4;
    if (frow0 + 16 <= N) {
      short8 b[6];
#pragma unroll
      for (int f = 0; f < 6; ++f)
        b[f] = *(const short8*)(w2s + f * 512 + lane * 8);
      short8 a[2];
#pragma unroll
      for (int ks = 0; ks < 2; ++ks) {
        int lr = wave * 16 + m;
        int p = ks * 4 + q;
        a[ks] = *(const short8*)&hsm[lr][p ^ (lr & 7)];
      }
      f32x4 z = {0.f, 0.f, 0.f, 0.f};
      f32x4 acc2[3] = {z, z, z};
#pragma unroll
      for (int ct = 0; ct < 3; ++ct)
#pragma unroll
        for (int ks = 0; ks < 2; ++ks)
          acc2[ct] = __builtin_amdgcn_mfma_f32_16x16x32_bf16(a[ks], b[ct * 2 + ks],
                                                             acc2[ct], 0, 0, 0);
#pragma unroll
      for (int ct = 0; ct < 3; ++ct)
#pragma unroll
        for (int r = 0; r < 4; ++r) {
          int row2 = frow0 + q * 4 + r;
          int c = ct * 16 + m;
          if (c < F_OUT) hw[(size_t)row2 * F_OUT + c] = f2bf(acc2[ct][r]);
        }
    } else {
      // tail rows: scalar from swizzled LDS
      for (int r = 0; r < 16; ++r) {
        int row2 = frow0 + r;
        if (row2 >= N) break;
        if (lane < F_OUT) {
          int lr = wave * 16 + r;
          float s = 0.f;
          for (int k = 0; k < F_HID; ++k) {
            const unsigned short* hp =
                (const unsigned short*)&hsm[lr][(k >> 3) ^ (lr & 7)];
            s = fmaf(bf2f(hp[k & 7]), W2[k * F_OUT + lane], s);
          }
          hw[(size_t)row2 * F_OUT + lane] = f2bf(s);
        }
      }
    }
  }
}

// ---------------------------------------------------------------------------
// Aggregation layer 2 + bias2 + log_softmax. hw rows are 40 bf16 (80 B);
// parts 0..4 carry data. 4-wide unrolled gather for MLP. Softmax reduces
// over the low-3 lane bits (parts 0..4 hold cols 0..39).
// ---------------------------------------------------------------------------
__global__ __launch_bounds__(256) void agg2_ls_k(const unsigned short* __restrict__ hw,
                                                 const int* __restrict__ row_ptr,
                                                 const int* __restrict__ csr,
                                                 const float* __restrict__ b2,
                                                 float* __restrict__ out, int N) {
  int wid = (blockIdx.x * 256 + threadIdx.x) >> 6;
  int lane = threadIdx.x & 63;
  int rowBase = wid * 8;
  if (rowBase >= N) return;
  int row = rowBase + (lane >> 3);
  int part = lane & 7;
  bool live = row < N;
  bool ld = live && (part < 5);

  int start = live ? row_ptr[row] : 0;
  int end   = live ? row_ptr[row + 1] : 0;

  float acc[8], bcc[8];
#pragma unroll
  for (int j = 0; j < 8; ++j) { acc[j] = 0.f; bcc[j] = 0.f; }

  int i = start;
  for (; i + 3 < end; i += 4) {
    int s0 = csr[i];
    int s1 = csr[i + 1];
    int s2 = csr[i + 2];
    int s3 = csr[i + 3];
    if (ld) {
      uint4 v0 = *(const uint4*)(hw + (size_t)s0 * F_OUT + (part << 3));
      uint4 v1 = *(const uint4*)(hw + (size_t)s1 * F_OUT + (part << 3));
      uint4 v2 = *(const uint4*)(hw + (size_t)s2 * F_OUT + (part << 3));
      uint4 v3 = *(const uint4*)(hw + (size_t)s3 * F_OUT + (part << 3));
      acc[0] += bflo(v0.x); acc[1] += bfhi(v0.x);
      acc[2] += bflo(v0.y); acc[3] += bfhi(v0.y);
      acc[4] += bflo(v0.z); acc[5] += bfhi(v0.z);
      acc[6] += bflo(v0.w); acc[7] += bfhi(v0.w);
      bcc[0] += bflo(v1.x); bcc[1] += bfhi(v1.x);
      bcc[2] += bflo(v1.y); bcc[3] += bfhi(v1.y);
      bcc[4] += bflo(v1.z); bcc[5] += bfhi(v1.z);
      bcc[6] += bflo(v1.w); bcc[7] += bfhi(v1.w);
      acc[0] += bflo(v2.x); acc[1] += bfhi(v2.x);
      acc[2] += bflo(v2.y); acc[3] += bfhi(v2.y);
      acc[4] += bflo(v2.z); acc[5] += bfhi(v2.z);
      acc[6] += bflo(v2.w); acc[7] += bfhi(v2.w);
      bcc[0] += bflo(v3.x); bcc[1] += bfhi(v3.x);
      bcc[2] += bflo(v3.y); bcc[3] += bfhi(v3.y);
      bcc[4] += bflo(v3.z); bcc[5] += bfhi(v3.z);
      bcc[6] += bflo(v3.w); bcc[7] += bfhi(v3.w);
    }
  }
  for (; i < end; ++i) {
    int s = csr[i];
    if (ld) {
      uint4 v = *(const uint4*)(hw + (size_t)s * F_OUT + (part << 3));
      acc[0] += bflo(v.x); acc[1] += bfhi(v.x);
      acc[2] += bflo(v.y); acc[3] += bfhi(v.y);
      acc[4] += bflo(v.z); acc[5] += bfhi(v.z);
      acc[6] += bflo(v.w); acc[7] += bfhi(v.w);
    }
  }

  bool valid = ld;
  float vj[8];
  float m = -3.4e38f;
  if (valid) {
    int c0 = part << 3;
    float4 bA = *(const float4*)(b2 + c0);
    float4 bB = *(const float4*)(b2 + c0 + 4);
    vj[0] = acc[0] + bcc[0] + bA.x; vj[1] = acc[1] + bcc[1] + bA.y;
    vj[2] = acc[2] + bcc[2] + bA.z; vj[3] = acc[3] + bcc[3] + bA.w;
    vj[4] = acc[4] + bcc[4] + bB.x; vj[5] = acc[5] + bcc[5] + bB.y;
    vj[6] = acc[6] + bcc[6] + bB.z; vj[7] = acc[7] + bcc[7] + bB.w;
#pragma unroll
    for (int j = 0; j < 8; ++j) m = fmaxf(m, vj[j]);
  }
#pragma unroll
  for (int off = 1; off < 8; off <<= 1) m = fmaxf(m, __shfl_xor(m, off, 64));
  float ex = 0.f;
  if (valid) {
#pragma unroll
    for (int j = 0; j < 8; ++j) ex += __expf(vj[j] - m);
  }
#pragma unroll
  for (int off = 1; off < 8; off <<= 1) ex += __shfl_xor(ex, off, 64);
  float lse = __logf(ex) + m;

  if (valid) {
    int c0 = part << 3;
    float* op = out + (size_t)row * F_OUT + c0;
    *(float4*)op = make_float4(vj[0] - lse, vj[1] - lse, vj[2] - lse, vj[3] - lse);
    *(float4*)(op + 4) = make_float4(vj[4] - lse, vj[5] - lse, vj[6] - lse, vj[7] - lse);
  }
}

// ---------------------------------------------------------------------------
// ws layout (≈28 MB):
//   regA : xw[N,64] bf16
//   regB : ebuf[E] u32 — reused as hw[N,40] bf16 (ebuf dead after build_k)
//   row_ptr : N+1 | csr : E | counts : M+1 | psum : 256 | w2s : 3072
// ---------------------------------------------------------------------------
extern "C" void kernel_launch(void* const* d_in, const int* in_sizes, int n_in,
                              void* d_out, int out_size, void* d_ws, size_t ws_size,
                              hipStream_t stream) {
  const float* x  = (const float*)d_in[0];
  const int*   ei = (const int*)d_in[1];
  const float* W1 = (const float*)d_in[2];
  const float* b1 = (const float*)d_in[3];
  const float* W2 = (const float*)d_in[4];
  const float* b2 = (const float*)d_in[5];

  int N = in_sizes[0] / F_IN;
  int E = in_sizes[1] / 2;

  char* base = (char*)d_ws;
  size_t szA = (size_t)N * F_HID * sizeof(unsigned short);
  size_t szEb = (size_t)E * sizeof(unsigned);
  size_t szHw = (size_t)N * F_OUT * sizeof(unsigned short);
  size_t szB = (szEb > szHw) ? szEb : szHw;
  unsigned short* xw = (unsigned short*)base;
  char* regB = base + ((szA + 255) & ~(size_t)255);
  unsigned* ebuf       = (unsigned*)regB;
  unsigned short* hw   = (unsigned short*)regB;
  int* row_ptr = (int*)(regB + ((szB + 255) & ~(size_t)255));
  int* csr     = row_ptr + N + 1;
  int* counts  = csr + E;
  float* out = (float*)d_out;

  int aggGrid  = (N * 8 + 255) / 256;      // 8 threads per row
  int gemmGrid = (N + 63) / 64;            // 4 waves x 16 rows per block
  int fusGrid  = (N + 31) / 32;            // 32 rows per block (agg1+gemm2)
  int NBLK  = (E + CHUNK - 1) / CHUNK;
  int NBUCK = (N + 511) >> BSH;
  int M = NBUCK * NBLK;
  int* psum = counts + M + 1;
  unsigned short* w2s = (unsigned short*)(psum + 256);
  int scanBlocks = (M + 2047) / 2048;

  // fused: pcount + w2s (blocks 0..NBLK-1) + gemm1 (remaining blocks)
  front_k<<<NBLK + gemmGrid, 256, 0, stream>>>(x, W1, W2, w2s, xw, N,
                                               ei, counts, E, NBLK, NBUCK);

  scanA_k<<<scanBlocks, 256, 0, stream>>>(counts, psum, M);
  scanC_k<<<scanBlocks, 256, 0, stream>>>(counts, psum, M, E, scanBlocks);
  partition_k<<<NBLK, 256, 0, stream>>>(counts, ei, ebuf, E, NBLK, NBUCK);
  build_k<<<NBUCK, BLD_T, 0, stream>>>(ebuf, counts, row_ptr, csr, N, E, NBLK);

  agg1g2_k<<<fusGrid, 256, 0, stream>>>(xw, row_ptr, csr, b1, w2s, W2, hw, N);
  agg2_ls_k<<<aggGrid, 256, 0, stream>>>(hw, row_ptr, csr, b2, out, N);
}